// Round 7
// baseline (832.565 us; speedup 1.0000x reference)
//
#include <hip/hip_runtime.h>
#include <math.h>

#define B_ 4
#define C_ 64
#define H_ 256
#define W_ 256
#define N_ 65536

// db3 filters. DEC_* from reference; REC_* = reversed DEC_*.
#define RL_INIT {0.3326705529509569f, 0.8068915093133388f, 0.4598775021193313f, -0.13501102001039084f, -0.08544127388224149f, 0.035226291882100656f}
#define RH_INIT {0.035226291882100656f, 0.08544127388224149f, -0.13501102001039084f, -0.4598775021193313f, 0.8068915093133388f, -0.3326705529509569f}
#define DL_INIT {0.035226291882100656f, -0.08544127388224149f, -0.13501102001039084f, 0.4598775021193313f, 0.8068915093133388f, 0.3326705529509569f}
#define DH_INIT {-0.3326705529509569f, 0.8068915093133388f, -0.4598775021193313f, -0.13501102001039084f, 0.08544127388224149f, 0.035226291882100656f}

// --------------------------------------------------------------------------
// K_MFE: fused q = idwt2(dw3(dwt2(x))) per 64w x 32h tile.  (unchanged, R6)
// --------------------------------------------------------------------------
__global__ __launch_bounds__(256) void k_mfe(
    const float* __restrict__ x,
    const float* __restrict__ w1, const float* __restrict__ w5,
    const float* __restrict__ w7, const float* __restrict__ w9,
    float* __restrict__ q, float* __restrict__ nq)
{
  const float RL[6] = RL_INIT, RH[6] = RH_INIT;
  const float DL[6] = DL_INIT, DH[6] = DH_INIT;
  const int bc = blockIdx.z;
  const int c  = bc & 63;
  const int h0 = blockIdx.y * 32, w0 = blockIdx.x * 64;

  __shared__ float A[3520];
  __shared__ float Bm[3344];
  float* xse = A;                     // [44][40]
  float* xso = A + 1760;              // [44][40]
  float* sub = A;                     // [4][21][38]
  float* lo2 = A;                     // [32][36]
  float* hi2 = A + 1152;              // [32][36]
  float* tlo = Bm;                    // [44][38]
  float* thi = Bm + 1672;             // [44][38]
  float* dt  = Bm;                    // [4][19][36]

  float wk[4][9];
#pragma unroll
  for (int i = 0; i < 9; ++i) {
    wk[0][i] = w1[c * 9 + i]; wk[1][i] = w5[c * 9 + i];
    wk[2][i] = w7[c * 9 + i]; wk[3][i] = w9[c * 9 + i];
  }

  {
    const float* xp = x + (size_t)bc * N_;
    const int xr0 = h0 - 6, xc0 = w0 - 8;
    for (int i = threadIdx.x; i < 44 * 39; i += 256) {
      int r = i / 39, c2 = i % 39;
      int gr = xr0 + r, gc = xc0 + c2 * 2;
      float2 v = make_float2(0.f, 0.f);
      if ((unsigned)gr < H_ && (unsigned)gc < W_)
        v = *(const float2*)&xp[gr * W_ + gc];
      xse[r * 40 + c2] = v.x;
      xso[r * 40 + c2] = v.y;
    }
  }
  __syncthreads();

  for (int i = threadIdx.x; i < 44 * 37; i += 256) {
    int r = i / 37, sw = i % 37;
    const float* xe = &xse[r * 40 + sw];
    const float* xo = &xso[r * 40 + sw];
    float e0 = xe[0], o0 = xo[0], e1 = xe[1], o1 = xo[1], e2 = xe[2], o2 = xo[2];
    tlo[r * 38 + sw] = e0*RL[0] + o0*RL[1] + e1*RL[2] + o1*RL[3] + e2*RL[4] + o2*RL[5];
    thi[r * 38 + sw] = e0*RH[0] + o0*RH[1] + e1*RH[2] + o1*RH[3] + e2*RH[4] + o2*RH[5];
  }
  __syncthreads();

  for (int i = threadIdx.x; i < 20 * 37; i += 256) {
    int sj = i / 37 + 1, sw = i % 37;
    int base = (2 * sj - 2) * 38 + sw;
    float ll = 0.f, lh = 0.f, hl = 0.f, hh = 0.f;
#pragma unroll
    for (int t = 0; t < 6; ++t) {
      float a = tlo[base + t * 38];
      float b = thi[base + t * 38];
      ll += a * RL[t]; lh += a * RH[t];
      hl += b * RL[t]; hh += b * RH[t];
    }
    sub[0 * 798 + sj * 38 + sw] = ll;
    sub[1 * 798 + sj * 38 + sw] = lh;
    sub[2 * 798 + sj * 38 + sw] = hl;
    sub[3 * 798 + sj * 38 + sw] = hh;
  }
  __syncthreads();

  for (int i = threadIdx.x; i < 18 * 34; i += 256) {
    int dr = i / 34 + 1, dc = i % 34 + 1;
#pragma unroll
    for (int s = 0; s < 4; ++s) {
      const float* sp = &sub[s * 798 + dr * 38 + dc];
      float acc = 0.f;
#pragma unroll
      for (int dy = 0; dy < 3; ++dy)
#pragma unroll
        for (int dx = 0; dx < 3; ++dx)
          acc += sp[dy * 38 + dx] * wk[s][dy * 3 + dx];
      dt[s * 684 + dr * 36 + dc] = acc;
    }
  }
  __syncthreads();

  for (int i = threadIdx.x; i < 32 * 34; i += 256) {
    int hl = i / 34, dc = i % 34 + 1;
    int idx0 = (hl >> 1) + 1;
    int po = hl & 1;
    float lo = 0.f, hi = 0.f;
#pragma unroll
    for (int o = 0; o < 3; ++o) {
      int rr = (idx0 + o) * 36 + dc;
      float cl = DL[2 * o + 1 - po], ch = DH[2 * o + 1 - po];
      lo += dt[0 * 684 + rr] * cl + dt[1 * 684 + rr] * ch;
      hi += dt[2 * 684 + rr] * cl + dt[3 * 684 + rr] * ch;
    }
    lo2[hl * 36 + dc] = lo; hi2[hl * 36 + dc] = hi;
  }
  __syncthreads();

  float nqacc = 0.f;
  for (int i = threadIdx.x; i < 2048; i += 256) {
    int hl = i >> 6, wl = i & 63;
    int ci0 = (wl >> 1) + 1;
    int po = wl & 1;
    const float* lr = &lo2[hl * 36 + ci0];
    const float* hr = &hi2[hl * 36 + ci0];
    float v = 0.f;
#pragma unroll
    for (int o = 0; o < 3; ++o)
      v += lr[o] * DL[2 * o + 1 - po] + hr[o] * DH[2 * o + 1 - po];
    q[(size_t)bc * N_ + (h0 + hl) * W_ + (w0 + wl)] = v;
    nqacc += v * v;
  }
#pragma unroll
  for (int off = 32; off > 0; off >>= 1) nqacc += __shfl_down(nqacc, off, 64);
  __shared__ float red4[4];
  if ((threadIdx.x & 63) == 0) red4[threadIdx.x >> 6] = nqacc;
  __syncthreads();
  if (threadIdx.x == 0)
    atomicAdd(&nq[bc], red4[0] + red4[1] + red4[2] + red4[3]);
}

// --------------------------------------------------------------------------
// K3: conv1x1 half.  R7: no X staging — x read via float4 from global (all
// 4 waves request identical addresses -> L1 broadcast).  LDS 49->17.4 KB.
// --------------------------------------------------------------------------
__global__ __launch_bounds__(256) void k_conv1x1(
    const float* __restrict__ x,
    const float* __restrict__ wq,
    const int co_off,
    float* __restrict__ out)
{
  const int b = blockIdx.y;
  const int n0 = blockIdx.x * 128;
  __shared__ float Wt[64][68];        // Wt[ci][co]

  for (int i = threadIdx.x; i < 4096; i += 256) {
    int co = i >> 6, ci = i & 63;
    Wt[ci][co] = wq[(co_off + co) * 64 + ci];
  }
  __syncthreads();

  const int px_g = threadIdx.x & 15;
  const int co_g = threadIdx.x >> 4;
  const int p0 = px_g * 4;
  const float* xb = x + (size_t)b * 64 * N_ + n0;
  float acc[4][8] = {};
#pragma unroll 4
  for (int ci = 0; ci < 64; ++ci) {
    float4 x0 = *(const float4*)&xb[(size_t)ci * N_ + p0];
    float4 x1 = *(const float4*)&xb[(size_t)ci * N_ + 64 + p0];
    float4 wv = *(const float4*)&Wt[ci][co_g * 4];
    const float wr[4] = {wv.x, wv.y, wv.z, wv.w};
    const float xr[8] = {x0.x, x0.y, x0.z, x0.w, x1.x, x1.y, x1.z, x1.w};
#pragma unroll
    for (int i = 0; i < 4; ++i)
#pragma unroll
      for (int j = 0; j < 8; ++j)
        acc[i][j] += wr[i] * xr[j];
  }
#pragma unroll
  for (int i = 0; i < 4; ++i) {
    float* op = &out[((size_t)b * 64 + co_g * 4 + i) * N_ + n0];
    *(float4*)&op[p0]      = make_float4(acc[i][0], acc[i][1], acc[i][2], acc[i][3]);
    *(float4*)&op[64 + p0] = make_float4(acc[i][4], acc[i][5], acc[i][6], acc[i][7]);
  }
}

// --------------------------------------------------------------------------
// K4k: dw3 on k-half (LDS halo tile) + S/nk reduction.  (unchanged, validated)
// --------------------------------------------------------------------------
__global__ __launch_bounds__(256) void k_kred(
    const float* __restrict__ kpre,
    const float* __restrict__ q,
    const float* __restrict__ wc,
    float* __restrict__ S,
    float* __restrict__ nk)
{
  const int b = blockIdx.z, hd = blockIdx.y, tile = blockIdx.x;
  const int h0 = (tile >> 3) * 32, w0 = (tile & 7) * 32;
  const int d = threadIdx.x >> 5, lane = threadIdx.x & 31;
  const int ck = hd * 8 + d;

  __shared__ float ks[8][34][36];

  for (int i = threadIdx.x; i < 9248; i += 256) {
    int ch = i / 1156, rem = i % 1156;
    int r = rem / 34, cc = rem % 34;
    int gh = h0 - 1 + r, gw = w0 - 1 + cc;
    float v = 0.f;
    if ((unsigned)gh < H_ && (unsigned)gw < W_)
      v = kpre[((size_t)b * 64 + hd * 8 + ch) * N_ + gh * W_ + gw];
    ks[ch][r][cc] = v;
  }
  __syncthreads();

  float wk[9];
#pragma unroll
  for (int i = 0; i < 9; ++i) wk[i] = wc[ck * 9 + i];
  const float* qp = q + ((size_t)b * 64 + hd * 8) * N_;

  float sacc[8] = {};
  float nkacc = 0.f;
  for (int r = 0; r < 32; ++r) {
    float kv = 0.f;
#pragma unroll
    for (int dy = 0; dy < 3; ++dy)
#pragma unroll
      for (int dx = 0; dx < 3; ++dx)
        kv += ks[d][r + dy][lane + dx] * wk[dy * 3 + dx];
    nkacc += kv * kv;
    const size_t npix = (size_t)(h0 + r) * W_ + w0 + lane;
#pragma unroll
    for (int cc = 0; cc < 8; ++cc)
      sacc[cc] += qp[(size_t)cc * N_ + npix] * kv;
  }
#pragma unroll
  for (int m = 16; m >= 1; m >>= 1) {
#pragma unroll
    for (int cc = 0; cc < 8; ++cc) sacc[cc] += __shfl_xor(sacc[cc], m, 64);
    nkacc += __shfl_xor(nkacc, m, 64);
  }
  if (lane == 0) {
#pragma unroll
    for (int cc = 0; cc < 8; ++cc)
      atomicAdd(&S[(((size_t)b * 8 + hd) * 8 + cc) * 8 + d], sacc[cc]);
    atomicAdd(&nk[((size_t)b * 8 + hd) * 8 + d], nkacc);
  }
}

// --------------------------------------------------------------------------
// K4v: dw3 on v-half, 32x32 LDS-tiled with halo.  (unchanged, validated)
// --------------------------------------------------------------------------
__global__ __launch_bounds__(256) void k_dw3v(
    const float* __restrict__ vpre,
    const float* __restrict__ wc,
    float* __restrict__ v)
{
  const int tile = blockIdx.x, cv = blockIdx.y, b = blockIdx.z;
  const int h0 = (tile >> 3) * 32, w0 = (tile & 7) * 32;
  __shared__ float vs[34][36];

  const float* vp = vpre + ((size_t)b * 64 + cv) * N_;
  for (int i = threadIdx.x; i < 1156; i += 256) {
    int r = i / 34, cc = i % 34;
    int gh = h0 - 1 + r, gw = w0 - 1 + cc;
    float val = 0.f;
    if ((unsigned)gh < H_ && (unsigned)gw < W_) val = vp[gh * W_ + gw];
    vs[r][cc] = val;
  }
  __syncthreads();

  float wk[9];
#pragma unroll
  for (int i = 0; i < 9; ++i) wk[i] = wc[(64 + cv) * 9 + i];

  for (int i = threadIdx.x; i < 1024; i += 256) {
    int r = i >> 5, cc = i & 31;
    float acc = 0.f;
#pragma unroll
    for (int dy = 0; dy < 3; ++dy)
#pragma unroll
      for (int dx = 0; dx < 3; ++dx)
        acc += vs[r + dy][cc + dx] * wk[dy * 3 + dx];
    v[((size_t)b * 64 + cv) * N_ + (h0 + r) * W_ + w0 + cc] = acc;
  }
}

// --------------------------------------------------------------------------
// K6: out = w_proj @ ((A1 v_r) * (A2 v_d)).  R7: P read from global (L1/L2-
// hot, 16 KB shared by all blocks) instead of LDS stage.  LDS 37.8->20.4 KB.
// --------------------------------------------------------------------------
__global__ __launch_bounds__(256) void k_out(
    const float* __restrict__ vr, const float* __restrict__ vd,
    const float* __restrict__ S1, const float* __restrict__ S2,
    const float* __restrict__ nq, const float* __restrict__ nk1,
    const float* __restrict__ nk2, const float* __restrict__ temp,
    const float* __restrict__ P,
    float* __restrict__ out)
{
  const int b = blockIdx.y;
  const int n0 = blockIdx.x * 64;
  __shared__ float us[64][64];
  __shared__ float a1s[512], a2s[512];

  // attention rows (one thread per (h,c); 8-wide softmax each)
  if (threadIdx.x < 64) {
    const int t = threadIdx.x;
    const int h = t >> 3;
    const float tp = temp[h];
    const float qn = fmaxf(sqrtf(nq[b * 64 + t]), 1e-12f);
    const size_t rowoff = ((size_t)b * 64 + t) * 8;
    const size_t noff = ((size_t)b * 8 + h) * 8;
    float l[8];
#pragma unroll
    for (int d = 0; d < 8; ++d)
      l[d] = S1[rowoff + d] / (qn * fmaxf(sqrtf(nk1[noff + d]), 1e-12f)) * tp;
    float m = l[0];
#pragma unroll
    for (int d = 1; d < 8; ++d) m = fmaxf(m, l[d]);
    float sum = 0.f;
#pragma unroll
    for (int d = 0; d < 8; ++d) { l[d] = expf(l[d] - m); sum += l[d]; }
#pragma unroll
    for (int d = 0; d < 8; ++d) a1s[t * 8 + d] = l[d] / sum;
#pragma unroll
    for (int d = 0; d < 8; ++d)
      l[d] = S2[rowoff + d] / fmaxf(sqrtf(nk2[noff + d]), 1e-12f) * tp;
    m = l[0];
#pragma unroll
    for (int d = 1; d < 8; ++d) m = fmaxf(m, l[d]);
    sum = 0.f;
#pragma unroll
    for (int d = 0; d < 8; ++d) { l[d] = expf(l[d] - m); sum += l[d]; }
#pragma unroll
    for (int d = 0; d < 8; ++d) a2s[t * 8 + d] = l[d] / sum;
  }
  __syncthreads();

  // phase A: gate in registers -> us
  {
    const int px = threadIdx.x & 63;
    const int g = threadIdx.x >> 6;
    const int ch0 = g * 16;
    float vrr[16], vdd[16];
#pragma unroll
    for (int j = 0; j < 16; ++j) {
      vrr[j] = vr[((size_t)b * 64 + ch0 + j) * N_ + n0 + px];
      vdd[j] = vd[((size_t)b * 64 + ch0 + j) * N_ + n0 + px];
    }
#pragma unroll
    for (int j = 0; j < 16; ++j) {
      const int c = ch0 + j;
      const int base = (j & 8);
      float s = 0.f, t2 = 0.f;
#pragma unroll
      for (int dd = 0; dd < 8; ++dd) {
        s  += a1s[c * 8 + dd] * vrr[base + dd];
        t2 += a2s[c * 8 + dd] * vdd[base + dd];
      }
      us[c][px] = s * t2;
    }
  }
  __syncthreads();

  // phase B: out[co][px] = sum_cc P[co][cc] * us[cc][px]; P row-major float4
  const int px_g = threadIdx.x & 15;
  const int co_g = threadIdx.x >> 4;
  const int p0 = px_g * 4;
  float acc[4][4] = {};
  for (int cc4 = 0; cc4 < 64; cc4 += 4) {
    float4 u0 = *(const float4*)&us[cc4 + 0][p0];
    float4 u1 = *(const float4*)&us[cc4 + 1][p0];
    float4 u2 = *(const float4*)&us[cc4 + 2][p0];
    float4 u3 = *(const float4*)&us[cc4 + 3][p0];
    const float u[4][4] = {{u0.x,u0.y,u0.z,u0.w},{u1.x,u1.y,u1.z,u1.w},
                           {u2.x,u2.y,u2.z,u2.w},{u3.x,u3.y,u3.z,u3.w}};
#pragma unroll
    for (int i = 0; i < 4; ++i) {
      float4 pv = *(const float4*)&P[(co_g * 4 + i) * 64 + cc4];
#pragma unroll
      for (int j = 0; j < 4; ++j)
        acc[i][j] += pv.x*u[0][j] + pv.y*u[1][j] + pv.z*u[2][j] + pv.w*u[3][j];
    }
  }
#pragma unroll
  for (int i = 0; i < 4; ++i)
    *(float4*)&out[((size_t)b * 64 + co_g * 4 + i) * N_ + n0 + p0] =
        make_float4(acc[i][0], acc[i][1], acc[i][2], acc[i][3]);
}

// --------------------------------------------------------------------------
extern "C" void kernel_launch(void* const* d_in, const int* in_sizes, int n_in,
                              void* d_out, int out_size, void* d_ws, size_t ws_size,
                              hipStream_t stream) {
  (void)in_sizes; (void)n_in; (void)out_size;
  const float* rgb  = (const float*)d_in[0];
  const float* dep  = (const float*)d_in[1];
  const float* temp = (const float*)d_in[2];
  const float* wqr  = (const float*)d_in[3];
  const float* wqd  = (const float*)d_in[4];
  const float* wqc  = (const float*)d_in[5];
  const float* w1   = (const float*)d_in[6];
  const float* w5   = (const float*)d_in[7];
  const float* w7   = (const float*)d_in[8];
  const float* w9   = (const float*)d_in[9];
  const float* wp   = (const float*)d_in[10];
  float* out = (float*)d_out;

  const size_t WS_NEEDED = 203475968;
  if (ws_size < WS_NEEDED) return;

  char* ws = (char*)d_ws;
  float* q   = (float*)(ws + 0);
  float* v_d = q;                      // q dead after depth k-reduce
  float* v_r = (float*)(ws + 67108864);
  float* big = (float*)(ws + 134217728);   // conv1x1 scratch (67.1 MB)
  char* redb = ws + 203440128;
  float* S1  = (float*)(redb);
  float* S2  = (float*)(redb + 8192);
  float* nq  = (float*)(redb + 16384);
  float* nk1 = (float*)(redb + 17408);
  float* nk2 = (float*)(redb + 18432);

  hipMemsetAsync(redb, 0, 19456, stream);

  // q = mfe(rgb), fully fused (64w x 32h tiles)
  k_mfe<<<dim3(4, 8, 256), 256, 0, stream>>>(rgb, w1, w5, w7, w9, q, nq);

  // rgb stream
  k_conv1x1<<<dim3(512, 4), 256, 0, stream>>>(rgb, wqr, 0, big);
  k_kred<<<dim3(64, 8, 4), 256, 0, stream>>>(big, q, wqc, S1, nk1);
  k_conv1x1<<<dim3(512, 4), 256, 0, stream>>>(rgb, wqr, 64, big);
  k_dw3v<<<dim3(64, 64, 4), 256, 0, stream>>>(big, wqc, v_r);

  // depth stream
  k_conv1x1<<<dim3(512, 4), 256, 0, stream>>>(dep, wqd, 0, big);
  k_kred<<<dim3(64, 8, 4), 256, 0, stream>>>(big, q, wqc, S2, nk2);
  k_conv1x1<<<dim3(512, 4), 256, 0, stream>>>(dep, wqd, 64, big);
  k_dw3v<<<dim3(64, 64, 4), 256, 0, stream>>>(big, wqc, v_d);

  // gated projection with fused attention softmaxes
  k_out<<<dim3(1024, 4), 256, 0, stream>>>(v_r, v_d, S1, S2, nq, nk1, nk2,
                                           temp, wp, out);
}